// Round 1
// baseline (1793.278 us; speedup 1.0000x reference)
//
#include <hip/hip_runtime.h>

#define N_NODES 100000
#define N_EDGES 1600000

// ---------------- edge kernels ----------------

// Degree count + layer-1 aggregation of z (3 features) in one pass.
__global__ __launch_bounds__(256) void k_count_agg1(
    const int* __restrict__ src, const int* __restrict__ dst,
    const float* __restrict__ z, float* __restrict__ cnt,
    float* __restrict__ agg1, int nE)
{
    int e = blockIdx.x * blockDim.x + threadIdx.x;
    if (e >= nE) return;
    int s = src[e], d = dst[e];
    atomicAdd(&cnt[d], 1.0f);
    atomicAdd(&agg1[d*3+0], z[s*3+0]);
    atomicAdd(&agg1[d*3+1], z[s*3+1]);
    atomicAdd(&agg1[d*3+2], z[s*3+2]);
}

__global__ __launch_bounds__(256) void k_inv(float* cnt, int n)
{
    int i = blockIdx.x * blockDim.x + threadIdx.x;
    if (i < n) cnt[i] = 1.0f / fmaxf(cnt[i], 1.0f);
}

// Generic W-wide (power of 2) feature aggregation: agg[dst] += x[src]
template<int W>
__global__ __launch_bounds__(256) void k_edge_agg(
    const int* __restrict__ src, const int* __restrict__ dst,
    const float* __restrict__ x, float* __restrict__ agg, int nE)
{
    long long t = (long long)blockIdx.x * blockDim.x + threadIdx.x;
    int e = (int)(t / W);
    int f = (int)(t % W);
    if (e >= nE) return;
    int s = src[e], d = dst[e];
    atomicAdd(&agg[(size_t)d*W + f], x[(size_t)s*W + f]);
}

// ---------------- node kernels ----------------

// Layer 1: h1[i][f] = relu(mean(z)[k]*W1l[k][f] + z[i][k]*W1r[k][f] + b1[f]); K=3, F=128
__global__ __launch_bounds__(256) void k_layer1(
    const float* __restrict__ agg1, const float* __restrict__ inv,
    const float* __restrict__ z,
    const float* __restrict__ W1l, const float* __restrict__ W1r,
    const float* __restrict__ b1, float* __restrict__ h1, int n)
{
    int t = blockIdx.x * blockDim.x + threadIdx.x;
    int i = t >> 7, f = t & 127;
    if (i >= n) return;
    float iv = inv[i];
    float m0 = agg1[i*3+0]*iv, m1 = agg1[i*3+1]*iv, m2 = agg1[i*3+2]*iv;
    float z0 = z[i*3+0],       z1 = z[i*3+1],       z2 = z[i*3+2];
    float acc = b1[f];
    acc += m0*W1l[0*128+f] + m1*W1l[1*128+f] + m2*W1l[2*128+f];
    acc += z0*W1r[0*128+f] + z1*W1r[1*128+f] + z2*W1r[2*128+f];
    h1[t] = fmaxf(acc, 0.0f);
}

// Register-blocked node GEMM.
// out[i][f] = op( sum_k X1[i][k]*W1[k][f]  (+ sum_k X2[i][k]*W2[k][f])
//                 (+ pre[i][f]*inv[i]) (+ bias[f]) ), op = relu?
// X1 rows optionally scaled by inv[i] during LDS staging (mean path).
template<int K, int F, int NPB, bool DUAL, bool SCALE1, bool ADDPRE, bool BIAS, bool RELU>
__global__ __launch_bounds__(256) void k_gemm(
    const float* __restrict__ X1, const float* __restrict__ W1,
    const float* __restrict__ X2, const float* __restrict__ W2,
    const float* __restrict__ pre, const float* __restrict__ inv,
    const float* __restrict__ bias, float* __restrict__ out, int n)
{
    constexpr int GROUPS = 256 / F;
    constexpr int NODES  = GROUPS * NPB;   // nodes per block
    __shared__ __align__(16) float sX1[NODES][K];
    __shared__ __align__(16) float sX2[DUAL ? NODES : 1][DUAL ? K : 1];

    const int tid  = threadIdx.x;
    const int g    = tid / F;
    const int f    = tid % F;
    const int base = blockIdx.x * NODES;

    // cooperative, vectorized staging of X rows into LDS
    {
        constexpr int TOT = NODES * K / 4;
        const float4* x1v = reinterpret_cast<const float4*>(X1 + (size_t)base * K);
        float4* s1v = reinterpret_cast<float4*>(&sX1[0][0]);
        #pragma unroll
        for (int o = tid; o < TOT; o += 256) {
            float4 v = x1v[o];
            if constexpr (SCALE1) {
                float s = inv[base + o / (K/4)];
                v.x *= s; v.y *= s; v.z *= s; v.w *= s;
            }
            s1v[o] = v;
        }
        if constexpr (DUAL) {
            const float4* x2v = reinterpret_cast<const float4*>(X2 + (size_t)base * K);
            float4* s2v = reinterpret_cast<float4*>(&sX2[0][0]);
            #pragma unroll
            for (int o = tid; o < TOT; o += 256) s2v[o] = x2v[o];
        }
        __syncthreads();
    }

    float acc[NPB];
    #pragma unroll
    for (int j = 0; j < NPB; ++j) acc[j] = 0.0f;

    for (int k4 = 0; k4 < K/4; ++k4) {
        const int k = k4 * 4;
        float w10 = W1[(k+0)*F+f], w11 = W1[(k+1)*F+f];
        float w12 = W1[(k+2)*F+f], w13 = W1[(k+3)*F+f];
        float w20, w21, w22, w23;
        if constexpr (DUAL) {
            w20 = W2[(k+0)*F+f]; w21 = W2[(k+1)*F+f];
            w22 = W2[(k+2)*F+f]; w23 = W2[(k+3)*F+f];
        }
        #pragma unroll
        for (int j = 0; j < NPB; ++j) {
            const float4 x = *reinterpret_cast<const float4*>(&sX1[g*NPB + j][k]);
            acc[j] += x.x*w10 + x.y*w11 + x.z*w12 + x.w*w13;
            if constexpr (DUAL) {
                const float4 y = *reinterpret_cast<const float4*>(&sX2[g*NPB + j][k]);
                acc[j] += y.x*w20 + y.y*w21 + y.z*w22 + y.w*w23;
            }
        }
    }

    #pragma unroll
    for (int j = 0; j < NPB; ++j) {
        int node = base + g*NPB + j;
        float v = acc[j];
        if constexpr (ADDPRE) v += pre[(size_t)node*F + f] * inv[node];
        if constexpr (BIAS)   v += bias[f];
        if constexpr (RELU)   v = fmaxf(v, 0.0f);
        out[(size_t)node*F + f] = v;
    }
}

// Final: out[i][f] = h3[i][k] @ W4[k][f] + b4[f]; K=64, F=40
__global__ __launch_bounds__(256) void k_out(
    const float* __restrict__ h3, const float* __restrict__ W4,
    const float* __restrict__ b4, float* __restrict__ out, int n)
{
    int t = blockIdx.x * blockDim.x + threadIdx.x;
    int i = t / 40, f = t % 40;
    if (i >= n) return;
    float acc = b4[f];
    #pragma unroll
    for (int k = 0; k < 64; ++k) acc += h3[i*64 + k] * W4[k*40 + f];
    out[t] = acc;
}

// ---------------- launch ----------------

extern "C" void kernel_launch(void* const* d_in, const int* in_sizes, int n_in,
                              void* d_out, int out_size, void* d_ws, size_t ws_size,
                              hipStream_t stream)
{
    const float* z   = (const float*)d_in[0];
    const int*   ei  = (const int*)d_in[1];
    const int*   src = ei;
    const int*   dst = ei + N_EDGES;
    const float* W1l = (const float*)d_in[2];
    const float* W1r = (const float*)d_in[3];
    const float* b1  = (const float*)d_in[4];
    const float* W2l = (const float*)d_in[5];
    const float* W2r = (const float*)d_in[6];
    const float* b2  = (const float*)d_in[7];
    const float* W3l = (const float*)d_in[8];
    const float* W3r = (const float*)d_in[9];
    const float* b3  = (const float*)d_in[10];
    const float* W4  = (const float*)d_in[11];
    const float* b4  = (const float*)d_in[12];
    float* out = (float*)d_out;

    float* ws  = (float*)d_ws;
    float* inv = ws;                                   // N floats (cnt -> inv)
    float* agg = ws + 100352;                          // N*128 floats (reused 3/128/64-wide)
    float* h1  = agg + (size_t)N_NODES * 128;          // N*128
    float* h2  = h1  + (size_t)N_NODES * 128;          // N*128
    float* t3  = h1;                                   // N*64 (h1 dead by then)
    float* h3  = h1 + (size_t)N_NODES * 64;            // N*64

    // degree count + layer-1 aggregation
    hipMemsetAsync(inv, 0, N_NODES * sizeof(float), stream);
    hipMemsetAsync(agg, 0, (size_t)N_NODES * 3 * sizeof(float), stream);
    k_count_agg1<<<(N_EDGES + 255) / 256, 256, 0, stream>>>(src, dst, z, inv, agg, N_EDGES);
    k_inv<<<(N_NODES + 255) / 256, 256, 0, stream>>>(inv, N_NODES);

    // layer 1 (K=3)
    k_layer1<<<((size_t)N_NODES * 128 + 255) / 256, 256, 0, stream>>>(
        agg, inv, z, W1l, W1r, b1, h1, N_NODES);

    // layer 2: aggregate h1 (128-wide), then dual GEMM
    hipMemsetAsync(agg, 0, (size_t)N_NODES * 128 * sizeof(float), stream);
    k_edge_agg<128><<<((size_t)N_EDGES * 128 + 255) / 256, 256, 0, stream>>>(src, dst, h1, agg, N_EDGES);
    k_gemm<128,128,16, true,  true,  false, true,  true ><<<3125, 256, 0, stream>>>(
        agg, W2l, h1, W2r, nullptr, inv, b2, h2, N_NODES);

    // layer 3: pre-transform t3 = h2 @ W3l (mean is linear), aggregate 64-wide
    k_gemm<128,64, 8, false, false, false, false, false><<<3125, 256, 0, stream>>>(
        h2, W3l, nullptr, nullptr, nullptr, nullptr, nullptr, t3, N_NODES);
    hipMemsetAsync(agg, 0, (size_t)N_NODES * 64 * sizeof(float), stream);
    k_edge_agg<64><<<((size_t)N_EDGES * 64 + 255) / 256, 256, 0, stream>>>(src, dst, t3, agg, N_EDGES);
    k_gemm<128,64, 8, false, false, true,  true,  true ><<<3125, 256, 0, stream>>>(
        h2, W3r, nullptr, nullptr, agg, inv, b3, h3, N_NODES);

    // output layer
    k_out<<<((size_t)N_NODES * 40 + 255) / 256, 256, 0, stream>>>(h3, W4, b4, out, N_NODES);
}

// Round 3
// 822.275 us; speedup vs baseline: 2.1809x; 2.1809x over previous
//
#include <hip/hip_runtime.h>

#define N_NODES 100000
#define N_EDGES 1600000

// ================= CSR build =================

__global__ __launch_bounds__(256) void k_hist(
    const int* __restrict__ dst, int* __restrict__ deg, int nE)
{
    int e = blockIdx.x * blockDim.x + threadIdx.x;
    if (e < nE) atomicAdd(&deg[dst[e]], 1);
}

// block b sums deg[b*1024 .. b*1024+1024) -> bsum[b]
__global__ __launch_bounds__(256) void k_chunk_sum(
    const int* __restrict__ deg, int* __restrict__ bsum, int n)
{
    __shared__ int sred[4];
    int base = blockIdx.x * 1024;
    int s = 0;
    for (int i = threadIdx.x; i < 1024; i += 256) {
        int idx = base + i;
        s += (idx < n) ? deg[idx] : 0;
    }
    #pragma unroll
    for (int o = 32; o > 0; o >>= 1) s += __shfl_xor(s, o);
    if ((threadIdx.x & 63) == 0) sred[threadIdx.x >> 6] = s;
    __syncthreads();
    if (threadIdx.x == 0) bsum[blockIdx.x] = sred[0] + sred[1] + sred[2] + sred[3];
}

// single block: exclusive scan of bsum[0..nb) in place (nb <= 128)
__global__ __launch_bounds__(128) void k_scan_bsum(int* bsum, int nb)
{
    int tid = threadIdx.x;
    int v = (tid < nb) ? bsum[tid] : 0;
    int lane = tid & 63, w = tid >> 6;
    int inc = v;
    #pragma unroll
    for (int o = 1; o < 64; o <<= 1) { int t = __shfl_up(inc, o); if (lane >= o) inc += t; }
    __shared__ int wsum[2];
    if (lane == 63) wsum[w] = inc;
    __syncthreads();
    int base = (w == 1) ? wsum[0] : 0;
    if (tid < nb) bsum[tid] = base + inc - v;  // exclusive
}

// block b: exclusive scan of its 1024-chunk of deg, + bsum[b] -> rowptr (start offsets)
__global__ __launch_bounds__(256) void k_scan_final(
    const int* __restrict__ deg, const int* __restrict__ bsum,
    int* __restrict__ rowptr, int n)
{
    int tid = threadIdx.x;
    int idx0 = blockIdx.x * 1024 + tid * 4;
    int v[4]; int lsum = 0;
    #pragma unroll
    for (int j = 0; j < 4; ++j) { v[j] = (idx0 + j < n) ? deg[idx0 + j] : 0; lsum += v[j]; }
    int lane = tid & 63, w = tid >> 6;
    int inc = lsum;
    #pragma unroll
    for (int o = 1; o < 64; o <<= 1) { int t = __shfl_up(inc, o); if (lane >= o) inc += t; }
    __shared__ int wsum[4];
    if (lane == 63) wsum[w] = inc;
    __syncthreads();
    int wbase = 0;
    #pragma unroll
    for (int i = 0; i < 4; ++i) if (i < w) wbase += wsum[i];
    int excl = bsum[blockIdx.x] + wbase + inc - lsum;
    #pragma unroll
    for (int j = 0; j < 4; ++j) {
        if (idx0 + j < n) rowptr[idx0 + j] = excl;
        excl += v[j];
    }
}

// scatter src ids; atomicAdd shifts rowptr[i] -> end offset of node i
__global__ __launch_bounds__(256) void k_scatter(
    const int* __restrict__ src, const int* __restrict__ dst,
    int* __restrict__ rowptr, int* __restrict__ csr, int nE)
{
    int e = blockIdx.x * blockDim.x + threadIdx.x;
    if (e >= nE) return;
    int pos = atomicAdd(&rowptr[dst[e]], 1);
    csr[pos] = src[e];
}
// After k_scatter: node i's neighbors are csr[(i?rowptr[i-1]:0) .. rowptr[i])

// ================= aggregation (wave per node, atomic-free) =================

template<int F>
__global__ __launch_bounds__(256) void k_gather(
    const int* __restrict__ rowptr, const int* __restrict__ csr,
    const float* __restrict__ x, float* __restrict__ out, int n)
{
    int wid  = (blockIdx.x * 256 + threadIdx.x) >> 6;
    int lane = threadIdx.x & 63;
    if (wid >= n) return;
    int beg = wid ? rowptr[wid - 1] : 0;
    int end = rowptr[wid];

    if constexpr (F == 128) {
        float2 acc = {0.f, 0.f};
        for (int eb = beg; eb < end; eb += 64) {
            int cnt = min(64, end - eb);
            int my = (lane < cnt) ? csr[eb + lane] : 0;
            for (int j = 0; j < cnt; ++j) {
                int s = __shfl(my, j);
                float2 v = reinterpret_cast<const float2*>(x + (size_t)s * 128)[lane];
                acc.x += v.x; acc.y += v.y;
            }
        }
        float iv = 1.0f / fmaxf((float)(end - beg), 1.0f);
        acc.x *= iv; acc.y *= iv;
        reinterpret_cast<float2*>(out + (size_t)wid * 128)[lane] = acc;
    } else {
        float acc = 0.f;
        for (int eb = beg; eb < end; eb += 64) {
            int cnt = min(64, end - eb);
            int my = (lane < cnt) ? csr[eb + lane] : 0;
            for (int j = 0; j < cnt; ++j) {
                int s = __shfl(my, j);
                acc += x[(size_t)s * F + lane];
            }
        }
        float iv = 1.0f / fmaxf((float)(end - beg), 1.0f);
        out[(size_t)wid * F + lane] = acc * iv;
    }
}

// ================= layer 1 (fused gather of z + MLP), wave per node =================

__global__ __launch_bounds__(256) void k_l1(
    const int* __restrict__ rowptr, const int* __restrict__ csr,
    const float* __restrict__ z,
    const float* __restrict__ W1l, const float* __restrict__ W1r,
    const float* __restrict__ b1, float* __restrict__ h1, int n)
{
    int wid  = (blockIdx.x * 256 + threadIdx.x) >> 6;
    int lane = threadIdx.x & 63;
    if (wid >= n) return;
    int beg = wid ? rowptr[wid - 1] : 0;
    int end = rowptr[wid];
    float a0 = 0, a1 = 0, a2 = 0;
    for (int e = beg + lane; e < end; e += 64) {
        int s = csr[e];
        a0 += z[s * 3 + 0]; a1 += z[s * 3 + 1]; a2 += z[s * 3 + 2];
    }
    #pragma unroll
    for (int o = 32; o > 0; o >>= 1) {
        a0 += __shfl_xor(a0, o); a1 += __shfl_xor(a1, o); a2 += __shfl_xor(a2, o);
    }
    float iv = 1.0f / fmaxf((float)(end - beg), 1.0f);
    float m0 = a0 * iv, m1 = a1 * iv, m2 = a2 * iv;
    float z0 = z[wid * 3 + 0], z1 = z[wid * 3 + 1], z2 = z[wid * 3 + 2];
    #pragma unroll
    for (int v = 0; v < 2; ++v) {
        int f = lane + v * 64;
        float acc = b1[f]
            + m0 * W1l[f] + m1 * W1l[128 + f] + m2 * W1l[256 + f]
            + z0 * W1r[f] + z1 * W1r[128 + f] + z2 * W1r[256 + f];
        h1[(size_t)wid * 128 + f] = fmaxf(acc, 0.0f);
    }
}

// ================= node GEMMs =================

// out[i][f] = op( X1[i][:]@W1[:,f] (+ X2[i][:]@W2[:,f]) (+ pre[i][f]) (+ bias[f]) )
template<int K, int F, int NPB, bool DUAL, bool ADDPRE, bool BIAS, bool RELU>
__global__ __launch_bounds__(256) void k_gemm(
    const float* __restrict__ X1, const float* __restrict__ W1,
    const float* __restrict__ X2, const float* __restrict__ W2,
    const float* __restrict__ pre, const float* __restrict__ bias,
    float* __restrict__ out, int n)
{
    constexpr int GROUPS = 256 / F;
    constexpr int NODES  = GROUPS * NPB;
    __shared__ __align__(16) float sX1[NODES][K];
    __shared__ __align__(16) float sX2[DUAL ? NODES : 1][DUAL ? K : 1];

    const int tid  = threadIdx.x;
    const int g    = tid / F;
    const int f    = tid % F;
    const int base = blockIdx.x * NODES;

    {
        constexpr int TOT = NODES * K / 4;
        const float4* x1v = reinterpret_cast<const float4*>(X1 + (size_t)base * K);
        float4* s1v = reinterpret_cast<float4*>(&sX1[0][0]);
        for (int o = tid; o < TOT; o += 256) s1v[o] = x1v[o];
        if constexpr (DUAL) {
            const float4* x2v = reinterpret_cast<const float4*>(X2 + (size_t)base * K);
            float4* s2v = reinterpret_cast<float4*>(&sX2[0][0]);
            for (int o = tid; o < TOT; o += 256) s2v[o] = x2v[o];
        }
        __syncthreads();
    }

    float acc[NPB];
    #pragma unroll
    for (int j = 0; j < NPB; ++j) acc[j] = 0.0f;

    for (int k4 = 0; k4 < K / 4; ++k4) {
        const int k = k4 * 4;
        float w10 = W1[(k+0)*F+f], w11 = W1[(k+1)*F+f];
        float w12 = W1[(k+2)*F+f], w13 = W1[(k+3)*F+f];
        float w20, w21, w22, w23;
        if constexpr (DUAL) {
            w20 = W2[(k+0)*F+f]; w21 = W2[(k+1)*F+f];
            w22 = W2[(k+2)*F+f]; w23 = W2[(k+3)*F+f];
        }
        #pragma unroll
        for (int j = 0; j < NPB; ++j) {
            const float4 x = *reinterpret_cast<const float4*>(&sX1[g*NPB + j][k]);
            acc[j] += x.x*w10 + x.y*w11 + x.z*w12 + x.w*w13;
            if constexpr (DUAL) {
                const float4 y = *reinterpret_cast<const float4*>(&sX2[g*NPB + j][k]);
                acc[j] += y.x*w20 + y.y*w21 + y.z*w22 + y.w*w23;
            }
        }
    }

    #pragma unroll
    for (int j = 0; j < NPB; ++j) {
        int node = base + g*NPB + j;
        float v = acc[j];
        if constexpr (ADDPRE) v += pre[(size_t)node*F + f];
        if constexpr (BIAS)   v += bias[f];
        if constexpr (RELU)   v = fmaxf(v, 0.0f);
        out[(size_t)node*F + f] = v;
    }
}

// Final: out[i][f] = h3[i][:] @ W4[:,f] + b4[f]; K=64, F=40
__global__ __launch_bounds__(256) void k_out(
    const float* __restrict__ h3, const float* __restrict__ W4,
    const float* __restrict__ b4, float* __restrict__ out, int n)
{
    int t = blockIdx.x * blockDim.x + threadIdx.x;
    int i = t / 40, f = t % 40;
    if (i >= n) return;
    float acc = b4[f];
    #pragma unroll
    for (int k = 0; k < 64; ++k) acc += h3[i*64 + k] * W4[k*40 + f];
    out[t] = acc;
}

// ================= launch =================

extern "C" void kernel_launch(void* const* d_in, const int* in_sizes, int n_in,
                              void* d_out, int out_size, void* d_ws, size_t ws_size,
                              hipStream_t stream)
{
    const float* z   = (const float*)d_in[0];
    const int*   ei  = (const int*)d_in[1];
    const int*   src = ei;
    const int*   dst = ei + N_EDGES;
    const float* W1l = (const float*)d_in[2];
    const float* W1r = (const float*)d_in[3];
    const float* b1  = (const float*)d_in[4];
    const float* W2l = (const float*)d_in[5];
    const float* W2r = (const float*)d_in[6];
    const float* b2  = (const float*)d_in[7];
    const float* W3l = (const float*)d_in[8];
    const float* W3r = (const float*)d_in[9];
    const float* b3  = (const float*)d_in[10];
    const float* W4  = (const float*)d_in[11];
    const float* b4  = (const float*)d_in[12];
    float* out = (float*)d_out;

    // workspace layout
    float* agg = (float*)d_ws;                          // N*128 floats
    float* h1  = agg + (size_t)N_NODES * 128;           // N*128
    float* h2  = h1  + (size_t)N_NODES * 128;           // N*128
    int* rowptr = (int*)(h2 + (size_t)N_NODES * 128);   // N ints
    int* csr    = rowptr + N_NODES;                     // E ints
    // deg/bsum alias the (still unused) agg region during CSR build
    int* deg  = (int*)agg;                              // N ints
    int* bsum = deg + N_NODES;                          // 128 ints
    float* t3 = h1;                                     // N*64 (h1 dead)
    float* h3 = h1 + (size_t)N_NODES * 64;              // N*64

    const int NB = (N_NODES + 1023) / 1024;             // 98

    // ---- CSR build ----
    hipMemsetAsync(deg, 0, N_NODES * sizeof(int), stream);
    k_hist      <<<(N_EDGES + 255) / 256, 256, 0, stream>>>(dst, deg, N_EDGES);
    k_chunk_sum <<<NB, 256, 0, stream>>>(deg, bsum, N_NODES);
    k_scan_bsum <<<1, 128, 0, stream>>>(bsum, NB);
    k_scan_final<<<NB, 256, 0, stream>>>(deg, bsum, rowptr, N_NODES);
    k_scatter   <<<(N_EDGES + 255) / 256, 256, 0, stream>>>(src, dst, rowptr, csr, N_EDGES);

    // ---- layer 1 (fused z-gather + MLP) ----
    k_l1<<<(N_NODES * 64 + 255) / 256, 256, 0, stream>>>(rowptr, csr, z, W1l, W1r, b1, h1, N_NODES);

    // ---- layer 2 ----
    k_gather<128><<<(N_NODES * 64 + 255) / 256, 256, 0, stream>>>(rowptr, csr, h1, agg, N_NODES);
    k_gemm<128,128,16, true,  false, true,  true ><<<3125, 256, 0, stream>>>(
        agg, W2l, h1, W2r, nullptr, b2, h2, N_NODES);

    // ---- layer 3 (pre-transform, mean is linear) ----
    k_gemm<128,64, 8, false, false, false, false><<<3125, 256, 0, stream>>>(
        h2, W3l, nullptr, nullptr, nullptr, nullptr, t3, N_NODES);
    k_gather<64><<<(N_NODES * 64 + 255) / 256, 256, 0, stream>>>(rowptr, csr, t3, agg, N_NODES);
    k_gemm<128,64, 8, false, true,  true,  true ><<<3125, 256, 0, stream>>>(
        h2, W3r, nullptr, nullptr, agg, b3, h3, N_NODES);

    // ---- output ----
    k_out<<<((size_t)N_NODES * 40 + 255) / 256, 256, 0, stream>>>(h3, W4, b4, out, N_NODES);
}

// Round 4
// 644.378 us; speedup vs baseline: 2.7830x; 1.2761x over previous
//
#include <hip/hip_runtime.h>

#define N_NODES 100000
#define N_EDGES 1600000
#define N_PAD   100032   // 1563 * 64
#define NBLK    1563

typedef __attribute__((ext_vector_type(4))) float f32x4;
typedef __attribute__((ext_vector_type(8))) short bf16x8;
typedef unsigned short ushort_t;
typedef unsigned int uint_t;

__device__ __forceinline__ ushort_t f2b(float f) {
    uint_t u = __float_as_uint(f);
    uint_t r = (u + 0x7FFFu + ((u >> 16) & 1u)) >> 16;   // RNE
    return (ushort_t)r;
}
__device__ __forceinline__ float b2f(ushort_t h) {
    return __uint_as_float(((uint_t)h) << 16);
}

// ================= CSR build =================

__global__ __launch_bounds__(256) void k_hist(
    const int* __restrict__ dst, int* __restrict__ deg, int nE)
{
    int e = blockIdx.x * blockDim.x + threadIdx.x;
    if (e < nE) atomicAdd(&deg[dst[e]], 1);
}

__global__ __launch_bounds__(256) void k_chunk_sum(
    const int* __restrict__ deg, int* __restrict__ bsum, int n)
{
    __shared__ int sred[4];
    int base = blockIdx.x * 1024;
    int s = 0;
    for (int i = threadIdx.x; i < 1024; i += 256) {
        int idx = base + i;
        s += (idx < n) ? deg[idx] : 0;
    }
    #pragma unroll
    for (int o = 32; o > 0; o >>= 1) s += __shfl_xor(s, o);
    if ((threadIdx.x & 63) == 0) sred[threadIdx.x >> 6] = s;
    __syncthreads();
    if (threadIdx.x == 0) bsum[blockIdx.x] = sred[0] + sred[1] + sred[2] + sred[3];
}

__global__ __launch_bounds__(128) void k_scan_bsum(int* bsum, int nb)
{
    int tid = threadIdx.x;
    int v = (tid < nb) ? bsum[tid] : 0;
    int lane = tid & 63, w = tid >> 6;
    int inc = v;
    #pragma unroll
    for (int o = 1; o < 64; o <<= 1) { int t = __shfl_up(inc, o); if (lane >= o) inc += t; }
    __shared__ int wsum[2];
    if (lane == 63) wsum[w] = inc;
    __syncthreads();
    int base = (w == 1) ? wsum[0] : 0;
    if (tid < nb) bsum[tid] = base + inc - v;
}

__global__ __launch_bounds__(256) void k_scan_final(
    const int* __restrict__ deg, const int* __restrict__ bsum,
    int* __restrict__ rowptr, int n)
{
    int tid = threadIdx.x;
    int idx0 = blockIdx.x * 1024 + tid * 4;
    int v[4]; int lsum = 0;
    #pragma unroll
    for (int j = 0; j < 4; ++j) { v[j] = (idx0 + j < n) ? deg[idx0 + j] : 0; lsum += v[j]; }
    int lane = tid & 63, w = tid >> 6;
    int inc = lsum;
    #pragma unroll
    for (int o = 1; o < 64; o <<= 1) { int t = __shfl_up(inc, o); if (lane >= o) inc += t; }
    __shared__ int wsum[4];
    if (lane == 63) wsum[w] = inc;
    __syncthreads();
    int wbase = 0;
    #pragma unroll
    for (int i = 0; i < 4; ++i) if (i < w) wbase += wsum[i];
    int excl = bsum[blockIdx.x] + wbase + inc - lsum;
    #pragma unroll
    for (int j = 0; j < 4; ++j) {
        if (idx0 + j < n) rowptr[idx0 + j] = excl;
        excl += v[j];
    }
}

__global__ __launch_bounds__(256) void k_scatter(
    const int* __restrict__ src, const int* __restrict__ dst,
    int* __restrict__ rowptr, int* __restrict__ csr, int nE)
{
    int e = blockIdx.x * blockDim.x + threadIdx.x;
    if (e >= nE) return;
    int pos = atomicAdd(&rowptr[dst[e]], 1);
    csr[pos] = src[e];
}
// After k_scatter: node i's neighbors are csr[(i?rowptr[i-1]:0) .. rowptr[i])

// ================= weight prep: bf16 transpose W^T[F][K] =================

__global__ __launch_bounds__(256) void k_prep_w(
    const float* __restrict__ W2l, const float* __restrict__ W2r,
    const float* __restrict__ W3l, const float* __restrict__ W3r,
    ushort_t* __restrict__ wt2l, ushort_t* __restrict__ wt2r,
    ushort_t* __restrict__ wt3l, ushort_t* __restrict__ wt3r)
{
    int id = blockIdx.x * 256 + threadIdx.x;
    if (id < 16384)      { int j = id;         int f = j >> 7, k = j & 127; wt2l[j] = f2b(W2l[k*128 + f]); }
    else if (id < 32768) { int j = id - 16384; int f = j >> 7, k = j & 127; wt2r[j] = f2b(W2r[k*128 + f]); }
    else if (id < 40960) { int j = id - 32768; int f = j >> 7, k = j & 127; wt3l[j] = f2b(W3l[k*64 + f]); }
    else if (id < 49152) { int j = id - 40960; int f = j >> 7, k = j & 127; wt3r[j] = f2b(W3r[k*64 + f]); }
}

// ================= layer 1 (fused z-gather + MLP), wave per node, bf16 out =================

__global__ __launch_bounds__(256) void k_l1(
    const int* __restrict__ rowptr, const int* __restrict__ csr,
    const float* __restrict__ z,
    const float* __restrict__ W1l, const float* __restrict__ W1r,
    const float* __restrict__ b1, ushort_t* __restrict__ h1b, int n)
{
    int wid  = (blockIdx.x * 256 + threadIdx.x) >> 6;
    int lane = threadIdx.x & 63;
    if (wid >= n) return;
    int beg = wid ? rowptr[wid - 1] : 0;
    int end = rowptr[wid];
    float a0 = 0, a1 = 0, a2 = 0;
    for (int e = beg + lane; e < end; e += 64) {
        int s = csr[e];
        a0 += z[s * 3 + 0]; a1 += z[s * 3 + 1]; a2 += z[s * 3 + 2];
    }
    #pragma unroll
    for (int o = 32; o > 0; o >>= 1) {
        a0 += __shfl_xor(a0, o); a1 += __shfl_xor(a1, o); a2 += __shfl_xor(a2, o);
    }
    float iv = 1.0f / fmaxf((float)(end - beg), 1.0f);
    float m0 = a0 * iv, m1 = a1 * iv, m2 = a2 * iv;
    float z0 = z[wid * 3 + 0], z1 = z[wid * 3 + 1], z2 = z[wid * 3 + 2];
    int f0 = lane * 2;
    float2 bl  = *(const float2*)(b1 + f0);
    float2 l0 = *(const float2*)(W1l + 0*128 + f0);
    float2 l1 = *(const float2*)(W1l + 1*128 + f0);
    float2 l2 = *(const float2*)(W1l + 2*128 + f0);
    float2 r0 = *(const float2*)(W1r + 0*128 + f0);
    float2 r1 = *(const float2*)(W1r + 1*128 + f0);
    float2 r2 = *(const float2*)(W1r + 2*128 + f0);
    float v0 = bl.x + m0*l0.x + m1*l1.x + m2*l2.x + z0*r0.x + z1*r1.x + z2*r2.x;
    float v1 = bl.y + m0*l0.y + m1*l1.y + m2*l2.y + z0*r0.y + z1*r1.y + z2*r2.y;
    v0 = fmaxf(v0, 0.0f); v1 = fmaxf(v1, 0.0f);
    uint_t u = (uint_t)f2b(v0) | ((uint_t)f2b(v1) << 16);
    *(uint_t*)(h1b + (size_t)wid * 128 + f0) = u;
}

// ================= gathers (bf16 in), atomic-free =================

// F=128: wave per node, lane handles feats 2*lane, 2*lane+1; bf16 out
__global__ __launch_bounds__(256) void k_gather128(
    const int* __restrict__ rowptr, const int* __restrict__ csr,
    const ushort_t* __restrict__ x, ushort_t* __restrict__ out, int n)
{
    int wid  = (blockIdx.x * 256 + threadIdx.x) >> 6;
    int lane = threadIdx.x & 63;
    if (wid >= n) return;
    int beg = wid ? rowptr[wid - 1] : 0;
    int end = rowptr[wid];
    float a0 = 0.f, a1 = 0.f;
    for (int eb = beg; eb < end; eb += 64) {
        int cnt = min(64, end - eb);
        int my = (lane < cnt) ? csr[eb + lane] : 0;
        for (int j = 0; j < cnt; ++j) {
            int s = __shfl(my, j);
            uint_t v = *(const uint_t*)(x + (size_t)s * 128 + lane * 2);
            a0 += b2f((ushort_t)(v & 0xffffu));
            a1 += b2f((ushort_t)(v >> 16));
        }
    }
    float iv = 1.0f / fmaxf((float)(end - beg), 1.0f);
    uint_t u = (uint_t)f2b(a0 * iv) | ((uint_t)f2b(a1 * iv) << 16);
    *(uint_t*)(out + (size_t)wid * 128 + lane * 2) = u;
}

// F=64: half-wave per node, f32 out (consumed as post-GEMM addend)
__global__ __launch_bounds__(256) void k_gather64(
    const int* __restrict__ rowptr, const int* __restrict__ csr,
    const ushort_t* __restrict__ x, float* __restrict__ out, int n)
{
    int w    = (blockIdx.x * 256 + threadIdx.x) >> 6;
    int lane = threadIdx.x & 63;
    int sub  = lane >> 5, sl = lane & 31;
    int node = w * 2 + sub;
    if (node >= n) return;
    int beg = node ? rowptr[node - 1] : 0;
    int end = rowptr[node];
    float a0 = 0.f, a1 = 0.f;
    for (int eb = beg; eb < end; eb += 32) {
        int cnt = min(32, end - eb);
        int my = (sl < cnt) ? csr[eb + sl] : 0;
        for (int j = 0; j < cnt; ++j) {
            int s = __shfl(my, sub * 32 + j);
            uint_t v = *(const uint_t*)(x + (size_t)s * 64 + sl * 2);
            a0 += b2f((ushort_t)(v & 0xffffu));
            a1 += b2f((ushort_t)(v >> 16));
        }
    }
    float iv = 1.0f / fmaxf((float)(end - beg), 1.0f);
    float2 r; r.x = a0 * iv; r.y = a1 * iv;
    *(float2*)(out + (size_t)node * 64 + sl * 2) = r;
}

// ================= MFMA node GEMM =================
// out[i][f] = op( X1[i][:]@W1[:,f] (+ X2[i][:]@W2[:,f]) (+ pre[i][f]) (+ bias[f]) )
// X: [N_PAD][128] bf16 row-major. Wt: [F][128] bf16 (W transposed). 64 nodes/block, 4 waves.
template<int F, bool DUAL, bool ADDPRE, bool BIAS, bool RELU, bool OUTBF>
__global__ __launch_bounds__(256) void k_mfma(
    const ushort_t* __restrict__ X1, const ushort_t* __restrict__ Wt1,
    const ushort_t* __restrict__ X2, const ushort_t* __restrict__ Wt2,
    const float* __restrict__ pre, const float* __restrict__ bias,
    void* __restrict__ outv)
{
    constexpr int NB = F / 16;
    __shared__ short sX[(DUAL ? 2 : 1) * 64 * 128];
    const int tid  = threadIdx.x;
    const int wv   = tid >> 6, lane = tid & 63;
    const int hi   = lane >> 4, lo = lane & 15;
    const int base = blockIdx.x * 64;

    // stage X tiles: [64 rows][16 chunks of 16B], XOR-swizzled (c ^= row&7) -> 2-way-free ds_read
    #pragma unroll
    for (int m = 0; m < (DUAL ? 2 : 1); ++m) {
        const float4* gv = reinterpret_cast<const float4*>((m ? X2 : X1) + (size_t)base * 128);
        short* sb = &sX[m * 64 * 128];
        #pragma unroll
        for (int it = 0; it < 4; ++it) {
            int o = it * 256 + tid;
            int row = o >> 4, c = o & 15;
            float4 v = gv[row * 16 + c];
            *reinterpret_cast<float4*>(&sb[(row * 16 + (c ^ (row & 7))) * 8]) = v;
        }
    }
    __syncthreads();

    f32x4 acc[NB];
    #pragma unroll
    for (int b = 0; b < NB; ++b) acc[b] = (f32x4){0.f, 0.f, 0.f, 0.f};

    const int row = wv * 16 + lo;   // A-frag row within tile
    #pragma unroll
    for (int kk = 0; kk < 4; ++kk) {
        int sw = (kk * 4 + hi) ^ (row & 7);
        bf16x8 a1 = *reinterpret_cast<const bf16x8*>(&sX[(row * 16 + sw) * 8]);
        bf16x8 a2;
        if constexpr (DUAL)
            a2 = *reinterpret_cast<const bf16x8*>(&sX[64 * 128 + (row * 16 + sw) * 8]);
        #pragma unroll
        for (int b = 0; b < NB; ++b) {
            bf16x8 w1 = *reinterpret_cast<const bf16x8*>(Wt1 + (size_t)(b * 16 + lo) * 128 + kk * 32 + hi * 8);
            acc[b] = __builtin_amdgcn_mfma_f32_16x16x32_bf16(a1, w1, acc[b], 0, 0, 0);
            if constexpr (DUAL) {
                bf16x8 w2 = *reinterpret_cast<const bf16x8*>(Wt2 + (size_t)(b * 16 + lo) * 128 + kk * 32 + hi * 8);
                acc[b] = __builtin_amdgcn_mfma_f32_16x16x32_bf16(a2, w2, acc[b], 0, 0, 0);
            }
        }
    }

    // C/D layout: col = lane&15, row = (lane>>4)*4 + reg  [m89-verified]
    #pragma unroll
    for (int b = 0; b < NB; ++b) {
        #pragma unroll
        for (int r = 0; r < 4; ++r) {
            int node = base + wv * 16 + hi * 4 + r;
            int f    = b * 16 + lo;
            float v  = acc[b][r];
            if constexpr (ADDPRE) v += pre[(size_t)node * F + f];
            if constexpr (BIAS)   v += bias[f];
            if constexpr (RELU)   v = fmaxf(v, 0.0f);
            if constexpr (OUTBF)  ((ushort_t*)outv)[(size_t)node * F + f] = f2b(v);
            else                  ((float*)outv)[(size_t)node * F + f] = v;
        }
    }
}

// ================= output layer (f32 vector; K=64, F=40) =================

__global__ __launch_bounds__(256) void k_out(
    const float* __restrict__ h3, const float* __restrict__ W4,
    const float* __restrict__ b4, float* __restrict__ out, int n)
{
    int t = blockIdx.x * blockDim.x + threadIdx.x;
    int i = t / 40, f = t % 40;
    if (i >= n) return;
    float acc = b4[f];
    #pragma unroll
    for (int k = 0; k < 64; ++k) acc += h3[(size_t)i * 64 + k] * W4[k * 40 + f];
    out[t] = acc;
}

// ================= launch =================

extern "C" void kernel_launch(void* const* d_in, const int* in_sizes, int n_in,
                              void* d_out, int out_size, void* d_ws, size_t ws_size,
                              hipStream_t stream)
{
    const float* z   = (const float*)d_in[0];
    const int*   ei  = (const int*)d_in[1];
    const int*   src = ei;
    const int*   dst = ei + N_EDGES;
    const float* W1l = (const float*)d_in[2];
    const float* W1r = (const float*)d_in[3];
    const float* b1  = (const float*)d_in[4];
    const float* W2l = (const float*)d_in[5];
    const float* W2r = (const float*)d_in[6];
    const float* b2  = (const float*)d_in[7];
    const float* W3l = (const float*)d_in[8];
    const float* W3r = (const float*)d_in[9];
    const float* b3  = (const float*)d_in[10];
    const float* W4  = (const float*)d_in[11];
    const float* b4  = (const float*)d_in[12];
    float* out = (float*)d_out;

    // ---- workspace layout (all node arrays padded to N_PAD rows) ----
    ushort_t* h1b  = (ushort_t*)d_ws;                      // N_PAD*128 bf16
    ushort_t* aggb = h1b  + (size_t)N_PAD * 128;           // N_PAD*128 bf16
    ushort_t* h2b  = aggb + (size_t)N_PAD * 128;           // N_PAD*128 bf16
    ushort_t* t3b  = h2b  + (size_t)N_PAD * 128;           // N_PAD*64  bf16
    float* agg64   = (float*)(t3b + (size_t)N_PAD * 64);   // N_PAD*64  f32
    float* h3      = agg64 + (size_t)N_PAD * 64;           // N_PAD*64  f32
    int* rowptr    = (int*)(h3 + (size_t)N_PAD * 64);      // N ints
    int* csr       = rowptr + N_NODES;                     // E ints
    ushort_t* wt2l = (ushort_t*)(csr + N_EDGES);           // 128*128
    ushort_t* wt2r = wt2l + 128 * 128;
    ushort_t* wt3l = wt2r + 128 * 128;                     // 64*128
    ushort_t* wt3r = wt3l + 64 * 128;
    // deg/bsum alias h2b during CSR build (h2b written later)
    int* deg  = (int*)h2b;
    int* bsum = deg + N_NODES;

    const int NB = (N_NODES + 1023) / 1024;                // 98

    // ---- CSR build ----
    hipMemsetAsync(deg, 0, N_NODES * sizeof(int), stream);
    k_hist      <<<(N_EDGES + 255) / 256, 256, 0, stream>>>(dst, deg, N_EDGES);
    k_chunk_sum <<<NB, 256, 0, stream>>>(deg, bsum, N_NODES);
    k_scan_bsum <<<1, 128, 0, stream>>>(bsum, NB);
    k_scan_final<<<NB, 256, 0, stream>>>(deg, bsum, rowptr, N_NODES);
    k_scatter   <<<(N_EDGES + 255) / 256, 256, 0, stream>>>(src, dst, rowptr, csr, N_EDGES);

    // ---- weight prep (independent) ----
    k_prep_w<<<192, 256, 0, stream>>>(W2l, W2r, W3l, W3r, wt2l, wt2r, wt3l, wt3r);

    // ---- layer 1 ----
    k_l1<<<(N_NODES * 64 + 255) / 256, 256, 0, stream>>>(rowptr, csr, z, W1l, W1r, b1, h1b, N_NODES);

    // ---- layer 2 ----
    k_gather128<<<(N_NODES * 64 + 255) / 256, 256, 0, stream>>>(rowptr, csr, h1b, aggb, N_NODES);
    k_mfma<128, true,  false, true,  true,  true ><<<NBLK, 256, 0, stream>>>(
        aggb, wt2l, h1b, wt2r, nullptr, b2, h2b);

    // ---- layer 3 (pre-transform t3 = h2 @ W3l; mean is linear) ----
    k_mfma<64,  false, false, false, false, true ><<<NBLK, 256, 0, stream>>>(
        h2b, wt3l, nullptr, nullptr, nullptr, nullptr, t3b);
    k_gather64<<<((N_NODES + 1) / 2 * 64 + 255) / 256, 256, 0, stream>>>(rowptr, csr, t3b, agg64, N_NODES);
    k_mfma<64,  false, true,  true,  true,  false><<<NBLK, 256, 0, stream>>>(
        h2b, wt3r, nullptr, nullptr, agg64, b3, h3);

    // ---- output ----
    k_out<<<((size_t)N_NODES * 40 + 255) / 256, 256, 0, stream>>>(h3, W4, b4, out, N_NODES);
}